// Round 5
// baseline (227.966 us; speedup 1.0000x reference)
//
#include <hip/hip_runtime.h>
#include <hip/hip_bf16.h>

// Problem constants (B,T,H,W,D = 32,16,32,32,64)
#define B_   32
#define T_   16
#define H_   32
#define W_   32
#define D_   64
#define N_   16384          // T*H*W
#define BLK  256
#define BLK_S 1024          // select block size (16 waves)
#define KPT_S 16            // keys per thread in select (N_/BLK_S)
#define LOSS_BLOCKS 2048
#define LOSS_ITERS  16      // (B_*N_*D_/4) / (LOSS_BLOCKS*BLK)
#define NWORDS (B_*N_/64)   // 8192 u64 bitmask words

// ---------------------------------------------------------------------------
// K1: select. DISCOVERY (R4): d_out is HOST-PINNED memory (the 78us d_out
// poison fill shows ~0 HBM traffic). So: (a) vis float writes to d_out are
// PCIe posted writes -> use 16-consecutive-token-per-thread mapping + float4
// stores (wave posts 4KB contiguous, WC-friendly); (b) ALSO write a 64KB
// bitmask to d_ws (HBM) so the loss kernel never reads d_out over PCIe.
// Core search: R4's 16-round x 2-bit binary search, 1 barrier/round.
// ---------------------------------------------------------------------------
__global__ __launch_bounds__(BLK_S, 1) void select_kernel(
    const float* __restrict__ u_g,
    const float* __restrict__ logp_t,
    const float* __restrict__ logp_h,
    const float* __restrict__ logp_w,
    const float* __restrict__ u_k,
    float* __restrict__ vis_out,     // d_out + 1 (HOST memory, PCIe)
    double* __restrict__ invrc,      // ws: 32 doubles
    unsigned long long* __restrict__ bitmask)  // ws: 8192 u64 (bit=visible)
{
    const int b    = blockIdx.x;
    const int tid  = threadIdx.x;
    const int lane = tid & 63;
    const int wv   = tid >> 6;       // 0..15

    __shared__ float s_lt[T_], s_lh[H_], s_lw[W_];
    __shared__ unsigned long long s_part[2][16];  // parity-double-buffered
    __shared__ int s_cnt;
    __shared__ int s_list[2048];     // rare tie-path index list
    __shared__ unsigned short s_m16[BLK_S];       // per-thread 16-bit vis field

    if (tid < T_) s_lt[tid] = logp_t[b*T_ + tid];
    if (tid < H_) s_lh[tid] = logp_h[b*H_ + tid];
    if (tid < W_) s_lw[tid] = logp_w[b*W_ + tid];
    if (tid == 0) s_cnt = 0;
    __syncthreads();

    // ---- keys: thread owns 16 CONSECUTIVE tokens n = tid*16 + i ----
    // u_g via 4x float4 (64B/thread; wave instr covers 4KB, all lines used).
    // NUMERICS LOCKED: stepwise fp32 -logf(-logf(u)), add order (lt+lh)+lw —
    // absmax 0.0 in R1-R4. Do not alter.
    unsigned keys[KPT_S];
    const float4* ug4 = (const float4*)(u_g + b*N_);
#pragma unroll
    for (int q = 0; q < 4; ++q) {
        float4 uu = ug4[tid*4 + q];
        float uc[4] = {uu.x, uu.y, uu.z, uu.w};
#pragma unroll
        for (int c = 0; c < 4; ++c) {
            int   i = q*4 + c;
            int   n = tid*16 + i;
            float g = -logf(-logf(uc[c]));
            int t = n >> 10;            // / (H_*W_)
            int h = (n >> 5) & 31;
            int w = n & 31;
            float wsv = g + ((s_lt[t] + s_lh[h]) + s_lw[w]);
            unsigned bits = __float_as_uint(wsv);
            keys[i] = (bits & 0x80000000u) ? ~bits : (bits | 0x80000000u);
        }
    }

    // ---- k for this row (np.linspace + fp32 mod/trunc semantics) ----
    float u0    = u_k[0];
    float strat = (b == B_-1) ? 1.0f : (float)((double)b * (1.0/31.0));
    float rate  = fmodf(u0 + strat, 1.0f);
    int   k     = (int)(16384.0f * rate);
    k = k < 1 ? 1 : (k > N_-1 ? N_-1 : k);

    // ---- 16 rounds x 2 bits: max thr with count(keys >= thr) >= k ----
    unsigned thr = 0u;
    for (int r = 0; r < 16; ++r) {
        const int bp = 30 - 2*r;
        const unsigned c1 = thr | (1u << bp);
        const unsigned c2 = thr | (2u << bp);
        const unsigned c3 = thr | (3u << bp);
        unsigned long long cnt = 0ull;
#pragma unroll
        for (int i = 0; i < KPT_S; ++i) {
            unsigned kk = keys[i];
            cnt += (kk >= c1 ? 1ull : 0ull)
                 + (kk >= c2 ? (1ull << 21) : 0ull)
                 + (kk >= c3 ? (1ull << 42) : 0ull);
        }
        for (int off = 32; off > 0; off >>= 1) cnt += __shfl_down(cnt, off);
        if (lane == 0) s_part[r & 1][wv] = cnt;
        __syncthreads();
        unsigned long long tot = 0ull;
#pragma unroll
        for (int w2 = 0; w2 < 16; ++w2) tot += s_part[r & 1][w2];
        const int t1 = (int)(tot & 0x1FFFFFull);
        const int t2 = (int)((tot >> 21) & 0x1FFFFFull);
        const int t3 = (int)(tot >> 42);
        const unsigned v = (t3 >= k) ? 3u : (t2 >= k) ? 2u : (t1 >= k) ? 1u : 0u;
        thr |= v << bp;
        // parity buffer: next round writes the other slot; its barrier
        // protects same-parity reuse two rounds later.
    }

    // ---- count strictly-greater and equal (packed, one barrier) ----
    unsigned long long cnt2 = 0ull;
#pragma unroll
    for (int i = 0; i < KPT_S; ++i) {
        cnt2 += (keys[i] >  thr ? 1ull : 0ull)
              + (keys[i] == thr ? (1ull << 21) : 0ull);
    }
    for (int off = 32; off > 0; off >>= 1) cnt2 += __shfl_down(cnt2, off);
    if (lane == 0) s_part[0][wv] = cnt2;
    __syncthreads();
    unsigned long long tot2 = 0ull;
#pragma unroll
    for (int w2 = 0; w2 < 16; ++w2) tot2 += s_part[0][w2];
    const int count_gt = (int)(tot2 & 0x1FFFFFull);
    const int count_eq = (int)((tot2 >> 21) & 0x1FFFFFull);
    const int need_eq  = k - count_gt;   // in [1, count_eq] by construction

    // ---- rare tie path: index-ordered selection among equal keys ----
    const bool rare = (count_eq != need_eq);
    if (rare && count_eq <= 2048) {
#pragma unroll
        for (int i = 0; i < KPT_S; ++i) {
            if (keys[i] == thr) {
                int slot = atomicAdd(&s_cnt, 1);
                s_list[slot] = tid*16 + i;   // absolute token index
            }
        }
    }
    __syncthreads();

    // ---- build vis (16 consecutive floats/thread) + 16-bit field ----
    float vbuf[16];
    unsigned field = 0u;
#pragma unroll
    for (int i = 0; i < KPT_S; ++i) {
        int n = tid*16 + i;
        float v;
        if (keys[i] > thr) {
            v = 1.0f;
        } else if (keys[i] == thr) {
            if (!rare || count_eq > 2048) {
                v = 1.0f;                        // all equals visible (common)
            } else {
                int rk = 0;
                for (int j = 0; j < count_eq; ++j)
                    rk += (s_list[j] < n) ? 1 : 0;
                v = (rk < need_eq) ? 1.0f : 0.0f; // first need_eq by index
            }
        } else {
            v = 0.0f;
        }
        vbuf[i] = v;
        field |= (v != 0.0f ? 1u : 0u) << i;
    }

    // float4 stores: wave posts 4KB contiguous to host (WC-friendly)
    float4* vp = (float4*)(vis_out + b*N_ + tid*16);
#pragma unroll
    for (int q = 0; q < 4; ++q)
        vp[q] = make_float4(vbuf[q*4+0], vbuf[q*4+1], vbuf[q*4+2], vbuf[q*4+3]);

    // bitmask to HBM: 4 threads' fields -> one u64 word (bit t = token t vis)
    s_m16[tid] = (unsigned short)field;
    __syncthreads();
    if (tid < 256) {
        unsigned long long w =  (unsigned long long)s_m16[tid*4 + 0]
                             | ((unsigned long long)s_m16[tid*4 + 1] << 16)
                             | ((unsigned long long)s_m16[tid*4 + 2] << 32)
                             | ((unsigned long long)s_m16[tid*4 + 3] << 48);
        bitmask[b*256 + tid] = w;
    }

    if (tid == 0) {
        float rc = (float)(N_ - k) / (float)N_;  // exact: power-of-2 division
        invrc[b] = 1.0 / (double)rc;
    }
}

// ---------------------------------------------------------------------------
// K2: loss. Mask now comes from the HBM bitmask — 16 block-uniform u64 loads
// into LDS (zero per-lane traffic) instead of 0.5M PCIe vis reads. Score
// loads stay fully coalesced (1KB/wave-instr), predicates known before the
// unrolled loop -> 16 independent conditional loads (MLP-16), ~50% of score
// bytes skipped.
// ---------------------------------------------------------------------------
__global__ __launch_bounds__(BLK, 1) void loss_kernel(
    const float* __restrict__ score,
    const unsigned long long* __restrict__ bitmask,
    const double* __restrict__ invrc,    // ws: 32 doubles
    double* __restrict__ partial)        // ws: LOSS_BLOCKS doubles
{
    const int tid = threadIdx.x;
    __shared__ double s_w[B_];
    __shared__ unsigned long long s_mw[LOSS_ITERS];
    if (tid < B_) s_w[tid] = invrc[tid];
    // word index for iter i: (gtid>>10) + i*512; gtid>>10 == blockIdx>>2
    if (tid < LOSS_ITERS) s_mw[tid] = bitmask[(blockIdx.x >> 2) + tid*512];
    __syncthreads();

    const int gtid = blockIdx.x * BLK + tid;     // 0 .. 524287
    const int NT   = LOSS_BLOCKS * BLK;          // 524288
    const int bit  = (gtid >> 4) & 63;           // token bit, i-independent
    const float4* s4 = (const float4*)score;

    double a = 0.0;
#pragma unroll
    for (int i = 0; i < LOSS_ITERS; ++i) {
        if (!((s_mw[i] >> bit) & 1ull)) {        // masked -> contributes
            int f = gtid + i * NT;
            float4 x = s4[f];
            float  s = (x.x + x.y) + (x.z + x.w);
            a += (double)s * s_w[f >> 18];       // b = f / 262144
        }
    }

    for (int off = 32; off > 0; off >>= 1) a += __shfl_down(a, off);
    __shared__ double s_a[4];
    if ((tid & 63) == 0) s_a[tid >> 6] = a;
    __syncthreads();
    if (tid == 0) partial[blockIdx.x] = s_a[0] + s_a[1] + s_a[2] + s_a[3];
}

// ---------------------------------------------------------------------------
// K3: sum 2048 partials, finalize loss = acc / 2^25 (one PCIe dword write)
// ---------------------------------------------------------------------------
__global__ __launch_bounds__(BLK, 1) void finalize_kernel(
    const double* __restrict__ partial,
    float* __restrict__ out)
{
    const int tid = threadIdx.x;
    double t = 0.0;
    for (int i = tid; i < LOSS_BLOCKS; i += BLK) t += partial[i];
    for (int off = 32; off > 0; off >>= 1) t += __shfl_down(t, off);
    __shared__ double s_a[4];
    if ((tid & 63) == 0) s_a[tid >> 6] = t;
    __syncthreads();
    if (tid == 0)
        out[0] = (float)((s_a[0] + s_a[1] + s_a[2] + s_a[3]) / 33554432.0);
}

extern "C" void kernel_launch(void* const* d_in, const int* in_sizes, int n_in,
                              void* d_out, int out_size, void* d_ws, size_t ws_size,
                              hipStream_t stream) {
    const float* u_g    = (const float*)d_in[0];
    const float* logp_t = (const float*)d_in[1];
    const float* logp_h = (const float*)d_in[2];
    const float* logp_w = (const float*)d_in[3];
    const float* u_k    = (const float*)d_in[4];
    const float* score  = (const float*)d_in[5];

    float*  out     = (float*)d_out;     // HOST mem: [0]=loss, [1..]=visible
    double* wsd     = (double*)d_ws;     // device HBM scratch
    double* invrc   = wsd;                           // 32 doubles
    double* partial = wsd + B_;                      // 2048 doubles
    unsigned long long* bitmask =
        (unsigned long long*)(wsd + B_ + LOSS_BLOCKS);  // 8192 u64

    select_kernel<<<B_, BLK_S, 0, stream>>>(u_g, logp_t, logp_h, logp_w, u_k,
                                            out + 1, invrc, bitmask);
    loss_kernel<<<LOSS_BLOCKS, BLK, 0, stream>>>(score, bitmask, invrc, partial);
    finalize_kernel<<<1, BLK, 0, stream>>>(partial, out);
}